// Round 4
// baseline (1033.274 us; speedup 1.0000x reference)
//
#include <hip/hip_runtime.h>

// ---------------------------------------------------------------------------
// AlignmentForce — fused pipeline, hard-coded co-resident grid + guarded
// backup.
//
// Round-3 post-mortem: DIY barrier fusion passed but ran at grid 512
// (OccupancyPercent 24% == 2 blocks/CU) because
// hipOccupancyMaxActiveBlocksPerMultiprocessor returned 2 — every phase at
// half parallelism -> 287 us. Resources (100 VGPR <= 128 cap, 14.8 KB LDS
// -> 59 KB for 4/CU of 160 KB) permit 4 blocks/CU, so this round hard-codes
// grid = 1024 and ignores the query. Failure containment: barriers detect
// timeout (bounded spin), broken blocks stop writing, BC is idempotent
// (per-bucket psum overwrite + inv8 overwrite), and a guarded 512-block
// backup kernel (co-residency proven in round 3) re-runs BC/FZ/D iff the
// FUSED_OK flag is unset — worst case correct-but-slow, never wrong/hung.
//
// Algebra (validated prior session):
//   F_sum  = sum_c S_Fc,  S_Fc = -2k(Sp_c + n_c*bt_c - Sref_c)
//   T_sum  = 2k*Xpr - 2k*sum_c cross(Sp_c,bt_c) + sum_c cross(bt_c,S_Fc)
//            - cross(o, F_sum),  Xpr = sum_j cross(p_rec_j, ref_j)
//   o      = (pos_sum + sum_c nrec_c*bt_c) / R
//
// Phases (k_all, 1024 blocks x 256 thr, 4 blocks/CU co-resident):
//   A  : blocks [0,512): pocket reductions (4-way batched gathers);
//        blocks [512,1024): partition (atom,chain) records into 1024
//        8192-atom buckets + per-chain nrec counts.   [no sync needed]
//   BC : bucket b = bid: 8-KB LDS chain map -> coalesced inv8 write; dense
//        masked pos_sum -> psum[b][3] (overwrite; idempotent).
//   FZ : block 0: reduce psum + closed-form algebra.
//   D  : grid-strided 1024-atom tiles: LDS-staged streaming output,
//        dwordx4 stores (writes EVERY element; d_out is poisoned).
//
// ws layout:
//   floats [0..47] bt[16][3], [48..50] o, [52..54] F_mean, [56..58] T_mean
//   floats [64.. ] acc: [3..18] nrec[16], [19..21] Xpr,
//                       [22+c*10+{Sg3,Sref3,Sp3,npoc}]   ([0..2] unused)
//   bytes [4032] bar (k_all), [4036] bar2 (backup), [4040] FUSED_OK
//   bytes [4096..8191]  gcount[1024] (uint)
//   bytes [8192..20479] psum[1024][3] (float, overwritten by BC)
//   bytes [20480..+10.49M) grecords[1024][2560] (uint)
//   bytes [INV8_OFF..+N) inv8 chain map (fully written by BC)
// Only bytes [0,8192) are memset to 0 per launch.
// ---------------------------------------------------------------------------

typedef unsigned int uint32;
typedef unsigned char uchar;

#define MAXC 16
#define W_BT 0
#define W_O 48
#define W_FM 52
#define W_TM 56
#define W_ACC 64

#define BAR_OFF 4032
#define BAR2_OFF 4036
#define OK_OFF 4040
#define GCOUNT_OFF 4096
#define PSUM_OFF 8192
#define REC_OFF 20480
#define NBK 1024
#define BSH 13
#define BUCKET_ATOMS (1 << BSH)          // 8192
#define CAP 2560                         // mean 2048, sigma ~39 -> 13 sigma
#define INV8_OFF (REC_OFF + NBK * CAP * 4)

#define GRID_ALL 1024
#define GRID_BK 512
#define K1_KPT 16
#define K1_CHUNK (256 * K1_KPT)          // 4096 records per chunk

struct PartSh { uint32 hist[NBK]; uint32 curs[NBK]; uint32 base[NBK]; };  // 12 KB
struct PocSh  { float red[4][43]; float accL[3 + MAXC * 10]; };
struct MapSh  { uchar map_[BUCKET_ATOMS]; };                              // 8 KB
struct StageSh{ float stage[3328]; };                                     // 13.3 KB
union ShU { PartSh part; PocSh poc; MapSh map; StageSh st; };
struct MiscSh { float red7[4][7]; float sc[64]; float cnt16[MAXC]; float tot[192]; };

__device__ inline float waveSum(float v) {
#pragma unroll
  for (int off = 32; off > 0; off >>= 1) v += __shfl_down(v, off, 64);
  return v;
}

// DIY grid barrier: monotonic arrival counter (zeroed by launch memset).
// Returns true iff the target count was observed (false = timeout: not all
// blocks co-resident / a peer dropped out). Bounded spin: never hangs.
__device__ inline bool gridBar(uint32* bar, int nblk, uint32 phase, int* shOk) {
  __threadfence();                 // release: publish this block's writes
  __syncthreads();
  if (threadIdx.x == 0) {
    __hip_atomic_fetch_add(bar, 1u, __ATOMIC_ACQ_REL, __HIP_MEMORY_SCOPE_AGENT);
    const uint32 tgt = (uint32)nblk * phase;
    int ok = 0;
    for (int it = 0; it < 2048; ++it) {   // ~0.5 ms cap
      if (__hip_atomic_load(bar, __ATOMIC_ACQUIRE, __HIP_MEMORY_SCOPE_AGENT) >= tgt) {
        ok = 1; break;
      }
      __builtin_amdgcn_s_sleep(4);
    }
    *shOk = ok;
  }
  __syncthreads();
  __threadfence();                 // acquire: drop stale cached lines
  return *shOk != 0;
}

// ======================= Phase A ==========================================
__device__ void phaseA(const float* __restrict__ pos,
                       const float* __restrict__ ref_poc,
                       const int* __restrict__ rec_idx,
                       const int* __restrict__ cid,
                       const int* __restrict__ poc_idx,
                       const int* __restrict__ poc_cid,
                       int C, int R, int P,
                       uint32* __restrict__ gcount,
                       uint32* __restrict__ grecords,
                       float* __restrict__ ws,
                       ShU& sh, MiscSh& ms, int bid, int pbN, int rbN) {
  const int tid = threadIdx.x;
  if (bid < pbN) {
    // ---------------- pocket reductions (4-way batched gathers) ----------
    const int gsz = pbN * 256;
    if (C <= 4) {
      float vals[43];  // [0..2] Xpr, [3+cc*10+q] {Sg3,Sref3,Sp3,npoc}
#pragma unroll
      for (int v = 0; v < 43; ++v) vals[v] = 0.f;
      for (int rb = bid * 256 + tid; rb < P; rb += 4 * gsz) {
        int rr[4], i2[4], c2[4], ri[4];
        float g[4][3], p[4][3], rf[4][3];
#pragma unroll
        for (int q = 0; q < 4; ++q) {
          int r = rb + q * gsz;
          rr[q] = (r < P) ? r : -1;
        }
#pragma unroll
        for (int q = 0; q < 4; ++q) {       // wave 1: independent loads
          int r = (rr[q] < 0) ? 0 : rr[q];
          i2[q] = poc_idx[r];
          c2[q] = poc_cid[r];
        }
#pragma unroll
        for (int q = 0; q < 4; ++q) {       // wave 2: dependent on i2
          ri[q] = rec_idx[i2[q]];
          g[q][0] = pos[3 * i2[q] + 0];     // faithful reference bug:
          g[q][1] = pos[3 * i2[q] + 1];     // global positions @ rec-space idx
          g[q][2] = pos[3 * i2[q] + 2];
        }
#pragma unroll
        for (int q = 0; q < 4; ++q) {       // wave 3: dependent on ri
          int r = (rr[q] < 0) ? 0 : rr[q];
          p[q][0] = pos[3 * ri[q] + 0];
          p[q][1] = pos[3 * ri[q] + 1];
          p[q][2] = pos[3 * ri[q] + 2];
          rf[q][0] = ref_poc[3 * r + 0];
          rf[q][1] = ref_poc[3 * r + 1];
          rf[q][2] = ref_poc[3 * r + 2];
        }
#pragma unroll
        for (int q = 0; q < 4; ++q) {
          if (rr[q] >= 0) {
            vals[0] += p[q][1] * rf[q][2] - p[q][2] * rf[q][1];
            vals[1] += p[q][2] * rf[q][0] - p[q][0] * rf[q][2];
            vals[2] += p[q][0] * rf[q][1] - p[q][1] * rf[q][0];
#pragma unroll
            for (int cc = 0; cc < 4; ++cc) {
              bool m = (c2[q] == cc);
              float* a = &vals[3 + cc * 10];
              a[0] += m ? g[q][0] : 0.f; a[1] += m ? g[q][1] : 0.f;
              a[2] += m ? g[q][2] : 0.f;
              a[3] += m ? rf[q][0] : 0.f; a[4] += m ? rf[q][1] : 0.f;
              a[5] += m ? rf[q][2] : 0.f;
              a[6] += m ? p[q][0] : 0.f; a[7] += m ? p[q][1] : 0.f;
              a[8] += m ? p[q][2] : 0.f;
              a[9] += m ? 1.f : 0.f;
            }
          }
        }
      }
      const int wid = tid >> 6;
#pragma unroll
      for (int v = 0; v < 43; ++v) {
        float s = waveSum(vals[v]);
        if ((tid & 63) == 0) sh.poc.red[wid][v] = s;
      }
      __syncthreads();
      for (int t = tid; t < 43; t += 256)
        atomicAdd(&ws[W_ACC + 19 + t], sh.poc.red[0][t] + sh.poc.red[1][t] +
                                       sh.poc.red[2][t] + sh.poc.red[3][t]);
    } else {
      // generic fallback 5 <= C <= 16 (correctness over speed)
      float* accL = sh.poc.accL;
      for (int t = tid; t < 3 + MAXC * 10; t += 256) accL[t] = 0.f;
      __syncthreads();
      for (int r = bid * 256 + tid; r < P; r += pbN * 256) {
        int i2 = poc_idx[r];
        int c2 = poc_cid[r];
        int ri = rec_idx[i2];
        float gx = pos[3 * i2 + 0], gy = pos[3 * i2 + 1], gz = pos[3 * i2 + 2];
        float px = pos[3 * ri + 0], py = pos[3 * ri + 1], pz = pos[3 * ri + 2];
        float rx = ref_poc[3 * r + 0], ry = ref_poc[3 * r + 1], rz = ref_poc[3 * r + 2];
        atomicAdd(&accL[0], py * rz - pz * ry);
        atomicAdd(&accL[1], pz * rx - px * rz);
        atomicAdd(&accL[2], px * ry - py * rx);
        float* a = &accL[3 + c2 * 10];
        atomicAdd(&a[0], gx); atomicAdd(&a[1], gy); atomicAdd(&a[2], gz);
        atomicAdd(&a[3], rx); atomicAdd(&a[4], ry); atomicAdd(&a[5], rz);
        atomicAdd(&a[6], px); atomicAdd(&a[7], py); atomicAdd(&a[8], pz);
        atomicAdd(&a[9], 1.f);
      }
      __syncthreads();
      for (int t = tid; t < 3 + MAXC * 10; t += 256)
        if (accL[t] != 0.f) atomicAdd(&ws[W_ACC + 19 + t], accL[t]);
    }
  } else {
    // ---------------- partition records into buckets + nrec counts --------
    const int pb = bid - pbN;
    uint32* hist = sh.part.hist;
    uint32* curs = sh.part.curs;
    uint32* base = sh.part.base;
    float c0 = 0.f, c1 = 0.f, c2 = 0.f, c3 = 0.f;
    if (C > 4) {
      for (int t = tid; t < MAXC; t += 256) ms.cnt16[t] = 0.f;
      __syncthreads();
    }
    for (int r0 = pb * K1_CHUNK; r0 < R; r0 += rbN * K1_CHUNK) {
      int cnt = R - r0; if (cnt > K1_CHUNK) cnt = K1_CHUNK;
      for (int t = tid; t < NBK; t += 256) { hist[t] = 0u; curs[t] = 0u; }
      __syncthreads();
      uint32 enc[K1_KPT];
#pragma unroll
      for (int j = 0; j < K1_KPT; ++j) {
        int t = tid + j * 256;
        uint32 e = 0xFFFFFFFFu;
        if (t < cnt) {
          uint32 idx = (uint32)rec_idx[r0 + t];
          uint32 c = (uint32)cid[r0 + t] & 255u;
          e = (idx << 8) | c;
          atomicAdd(&hist[idx >> BSH], 1u);
          if (C <= 4) {
            c0 += (c == 0u) ? 1.f : 0.f; c1 += (c == 1u) ? 1.f : 0.f;
            c2 += (c == 2u) ? 1.f : 0.f; c3 += (c == 3u) ? 1.f : 0.f;
          } else {
            atomicAdd(&ms.cnt16[c], 1.f);
          }
        }
        enc[j] = e;
      }
      __syncthreads();
      for (int t = tid; t < NBK; t += 256) {
        uint32 h = hist[t];
        base[t] = h ? atomicAdd(&gcount[t], h) : 0u;
      }
      __syncthreads();
#pragma unroll
      for (int j = 0; j < K1_KPT; ++j) {
        uint32 e = enc[j];
        if (e != 0xFFFFFFFFu) {
          uint32 b = e >> (8 + BSH);
          uint32 slot = base[b] + atomicAdd(&curs[b], 1u);
          if (slot < CAP) grecords[b * CAP + slot] = e;
        }
      }
      __syncthreads();
    }
    if (C <= 4) {
      float vv[4] = {c0, c1, c2, c3};
      const int wid = tid >> 6;
#pragma unroll
      for (int v = 0; v < 4; ++v) {
        float s = waveSum(vv[v]);
        if ((tid & 63) == 0) ms.red7[wid][v] = s;
      }
      __syncthreads();
      if (tid < 4)
        atomicAdd(&ws[W_ACC + 3 + tid], ms.red7[0][tid] + ms.red7[1][tid] +
                                        ms.red7[2][tid] + ms.red7[3][tid]);
    } else {
      __syncthreads();
      if (tid < C) atomicAdd(&ws[W_ACC + 3 + tid], ms.cnt16[tid]);
    }
  }
}

// ======================= Phase BC: bucket map + inv8 + psum ===============
// Idempotent: psum[b][*] and inv8 are pure overwrites -> safe to re-run.
__device__ void phaseBC(const float* __restrict__ pos,
                        const uint32* __restrict__ gcount,
                        const uint32* __restrict__ grecords,
                        int N, uchar* __restrict__ inv8,
                        float* __restrict__ psum,
                        ShU& sh, MiscSh& ms, int bid, int gridN) {
  const int tid = threadIdx.x;
  for (int b = bid; b < NBK; b += gridN) {
    const int a0 = b << BSH;
    float sx = 0.f, sy = 0.f, sz = 0.f;
    if (a0 < N) {                        // block-uniform
      int natoms = N - a0; if (natoms > BUCKET_ATOMS) natoms = BUCKET_ATOMS;
      uchar* map_ = sh.map.map_;
      uint4* m16 = (uint4*)map_;
      uint4 ff; ff.x = ff.y = ff.z = ff.w = 0xFFFFFFFFu;
      for (int t = tid; t < BUCKET_ATOMS / 16; t += 256) m16[t] = ff;
      __syncthreads();
      int n = (int)gcount[b]; if (n > CAP) n = CAP;
      for (int t = tid; t < n; t += 256) {
        uint32 e = grecords[b * CAP + t];
        map_[(e >> 8) & (BUCKET_ATOMS - 1)] = (uchar)(e & 255u);
      }
      __syncthreads();
      uchar* dst = inv8 + a0;
      if (natoms == BUCKET_ATOMS) {
        uint4* d16 = (uint4*)dst;
        for (int t = tid; t < BUCKET_ATOMS / 16; t += 256) d16[t] = m16[t];
      } else {
        for (int t = tid; t < natoms; t += 256) dst[t] = map_[t];
      }
      int ngf = natoms >> 2;
      const uchar4* m4 = (const uchar4*)map_;
      const float4* pos4 = (const float4*)pos;
      int g0 = a0 >> 2;
      for (int g = tid; g < ngf; g += 256) {
        float4 p0 = pos4[3 * (g0 + g) + 0];
        float4 p1 = pos4[3 * (g0 + g) + 1];
        float4 p2 = pos4[3 * (g0 + g) + 2];
        uchar4 m = m4[g];
        if (m.x != 255) { sx += p0.x; sy += p0.y; sz += p0.z; }
        if (m.y != 255) { sx += p0.w; sy += p1.x; sz += p1.y; }
        if (m.z != 255) { sx += p1.z; sy += p1.w; sz += p2.x; }
        if (m.w != 255) { sx += p2.y; sy += p2.z; sz += p2.w; }
      }
      int tb = natoms & 3;
      if (tid < tb) {
        int a = a0 + (ngf << 2) + tid;
        if (map_[(ngf << 2) + tid] != 255) {
          sx += pos[3 * a]; sy += pos[3 * a + 1]; sz += pos[3 * a + 2];
        }
      }
    }
    // per-bucket block reduce -> psum[b][0..2] (overwrite)
    float vv[3] = {sx, sy, sz};
    const int wid = tid >> 6;
#pragma unroll
    for (int v = 0; v < 3; ++v) {
      float s = waveSum(vv[v]);
      if ((tid & 63) == 0) ms.red7[wid][v] = s;
    }
    __syncthreads();
    if (tid < 3)
      psum[b * 3 + tid] = ms.red7[0][tid] + ms.red7[1][tid] +
                          ms.red7[2][tid] + ms.red7[3][tid];
    __syncthreads();                     // red7 + map reused next iteration
  }
}

// ======================= Phase FZ: psum reduce + closed-form ==============
__device__ void phaseFZ(const float* __restrict__ box,
                        const float* __restrict__ kp,
                        int C, int R, float* __restrict__ ws,
                        const float* __restrict__ psum,
                        MiscSh& ms, int bid) {
  if (bid != 0) return;
  const int tid = threadIdx.x;
  float sx = 0.f, sy = 0.f, sz = 0.f;
  for (int b = tid; b < NBK; b += 256) {
    sx += psum[3 * b + 0]; sy += psum[3 * b + 1]; sz += psum[3 * b + 2];
  }
  float vv[3] = {sx, sy, sz};
  const int wid = tid >> 6;
#pragma unroll
  for (int v = 0; v < 3; ++v) {
    float s = waveSum(vv[v]);
    if ((tid & 63) == 0) ms.red7[wid][v] = s;
  }
  for (int t = tid; t < 192; t += 256) ms.tot[t] = ws[W_ACC + t];
  __syncthreads();
  if (tid != 0) return;
  float* tot = ms.tot;
  tot[0] = ms.red7[0][0] + ms.red7[1][0] + ms.red7[2][0] + ms.red7[3][0];
  tot[1] = ms.red7[0][1] + ms.red7[1][1] + ms.red7[2][1] + ms.red7[3][1];
  tot[2] = ms.red7[0][2] + ms.red7[1][2] + ms.red7[2][2] + ms.red7[3][2];
  const float kk = kp[0];
  const float Rf = (float)R;
  const float* xp = &tot[19];
  float inv0 = 1.f / box[0], inv1 = 1.f / box[4], inv2 = 1.f / box[8];
  float ox = tot[0], oy = tot[1], oz = tot[2];
  float Fx = 0, Fy = 0, Fz = 0;
  float T1x = 0, T1y = 0, T1z = 0, T2x = 0, T2y = 0, T2z = 0;
  for (int c = 0; c < C; ++c) {
    float nrec = tot[3 + c];
    const float* a = &tot[22 + c * 10];
    float np = a[9];
    float invn = 1.f / np;
    float pcx = a[0] * invn, pcy = a[1] * invn, pcz = a[2] * invn;
    float rcx = a[3] * invn, rcy = a[4] * invn, rcz = a[5] * invn;
    float dx = rcx - pcx, dy = rcy - pcy, dz = rcz - pcz;
    float s3 = rintf(dz * inv2);
    dx -= s3 * box[6]; dy -= s3 * box[7]; dz -= s3 * box[8];
    float s2 = rintf(dy * inv1);
    dx -= s2 * box[3]; dy -= s2 * box[4]; dz -= s2 * box[5];
    float s1 = rintf(dx * inv0);
    float btx = s1 * box[0] + s2 * box[3] + s3 * box[6];
    float bty = s1 * box[1] + s2 * box[4] + s3 * box[7];
    float btz = s1 * box[2] + s2 * box[5] + s3 * box[8];
    ws[W_BT + c * 3 + 0] = btx;
    ws[W_BT + c * 3 + 1] = bty;
    ws[W_BT + c * 3 + 2] = btz;
    ox += nrec * btx; oy += nrec * bty; oz += nrec * btz;
    float SFx = -2.f * kk * (a[6] + np * btx - a[3]);
    float SFy = -2.f * kk * (a[7] + np * bty - a[4]);
    float SFz = -2.f * kk * (a[8] + np * btz - a[5]);
    Fx += SFx; Fy += SFy; Fz += SFz;
    T1x += a[7] * btz - a[8] * bty;
    T1y += a[8] * btx - a[6] * btz;
    T1z += a[6] * bty - a[7] * btx;
    T2x += bty * SFz - btz * SFy;
    T2y += btz * SFx - btx * SFz;
    T2z += btx * SFy - bty * SFx;
  }
  ox /= Rf; oy /= Rf; oz /= Rf;
  float Tx = 2.f * kk * xp[0] - 2.f * kk * T1x + T2x - (oy * Fz - oz * Fy);
  float Ty = 2.f * kk * xp[1] - 2.f * kk * T1y + T2y - (oz * Fx - ox * Fz);
  float Tz = 2.f * kk * xp[2] - 2.f * kk * T1z + T2z - (ox * Fy - oy * Fx);
  ws[W_O + 0] = ox; ws[W_O + 1] = oy; ws[W_O + 2] = oz;
  ws[W_FM + 0] = Fx / Rf; ws[W_FM + 1] = Fy / Rf; ws[W_FM + 2] = Fz / Rf;
  ws[W_TM + 0] = Tx / Rf; ws[W_TM + 1] = Ty / Rf; ws[W_TM + 2] = Tz / Rf;
}

// ======================= Phase D: streaming output ========================
// stage idx = k + k/12 (odd stride 13 per owner => conflict-free). Global
// range of a full tile starts at out-index 1+3072t (== 1 mod 4): 3 scalar
// floats, then 767 dwordx4 stores, then 1 scalar. Writes EVERY element.
__device__ void phaseD(const float* __restrict__ pos,
                       const uchar* __restrict__ inv8,
                       int N, const float* __restrict__ ws,
                       float* __restrict__ out,
                       ShU& sh, MiscSh& ms, int bid, int gridN) {
  const int tid = threadIdx.x;
  float* sc = ms.sc;
  if (tid < 64) sc[tid] = ws[tid];
  if (bid == 0 && tid == 0) out[0] = 0.f;  // energy scalar
  const int ntiles = (N + 1023) >> 10;
  for (int tile = bid; tile < ntiles; tile += gridN) {
    const int t0 = tile << 10;
    int nat = N - t0; if (nat > 1024) nat = 1024;
    const int nfl = nat * 3;
    float* stage = sh.st.stage;

    if (nat == 1024) {
      const float4* src4 = (const float4*)(pos + 3 * t0);
#pragma unroll
      for (int kk = 0; kk < 3; ++kk) {
        int v4 = tid + kk * 256;          // 0..767
        float4 p = src4[v4];
        int idx = 4 * v4 + v4 / 3;        // = g + g/12, g = 4*v4
        stage[idx + 0] = p.x; stage[idx + 1] = p.y;
        stage[idx + 2] = p.z; stage[idx + 3] = p.w;
      }
    } else {
      for (int k = tid; k < nfl; k += 256)
        stage[k + (int)((unsigned)k / 12u)] = pos[3 * t0 + k];
    }
    __syncthreads();

    float ox = sc[W_O + 0], oy = sc[W_O + 1], oz = sc[W_O + 2];
    float fmx = sc[W_FM + 0], fmy = sc[W_FM + 1], fmz = sc[W_FM + 2];
    float tmx = sc[W_TM + 0], tmy = sc[W_TM + 1], tmz = sc[W_TM + 2];

    uchar mc[4];
    if (nat == 1024) {
      uchar4 m = ((const uchar4*)(inv8 + t0))[tid];
      mc[0] = m.x; mc[1] = m.y; mc[2] = m.z; mc[3] = m.w;
    } else {
#pragma unroll
      for (int q = 0; q < 4; ++q) {
        int la = 4 * tid + q;
        mc[q] = (la < nat) ? inv8[t0 + la] : (uchar)255;
      }
    }
#pragma unroll
    for (int q = 0; q < 4; ++q) {
      int la = 4 * tid + q;
      if (la < nat) {
        float* s = &stage[13 * tid + 3 * q];
        float fx = 0.f, fy = 0.f, fz = 0.f;
        int c = mc[q];
        if (c != 255) {
          float cx = s[0] + sc[W_BT + 3 * c + 0] - ox;
          float cy = s[1] + sc[W_BT + 3 * c + 1] - oy;
          float cz = s[2] + sc[W_BT + 3 * c + 2] - oz;
          float inv = 1.f / (cx * cx + cy * cy + cz * cz);
          fx = fmx + (tmy * cz - tmz * cy) * inv;
          fy = fmy + (tmz * cx - tmx * cz) * inv;
          fz = fmz + (tmx * cy - tmy * cx) * inv;
        }
        s[0] = fx; s[1] = fy; s[2] = fz;   // own slots only
      }
    }
    __syncthreads();

    float* ob = out + 1 + 3 * t0;
    if (nat == 1024) {
#pragma unroll
      for (int kk = 0; kk < 3; ++kk) {
        int j = tid + kk * 256;
        if (j < 767) {
          int k = 3 + 4 * j;
          float4 v;
          v.x = stage[k + k / 12];
          v.y = stage[(k + 1) + (k + 1) / 12];
          v.z = stage[(k + 2) + (k + 2) / 12];
          v.w = stage[(k + 3) + (k + 3) / 12];
          *(float4*)(ob + k) = v;
        }
      }
      if (tid < 3) ob[tid] = stage[tid];               // k=0,1,2
      if (tid == 3) ob[3071] = stage[3071 + 3071 / 12];
    } else {
      for (int k = tid; k < nfl; k += 256)
        ob[k] = stage[k + (int)((unsigned)k / 12u)];
    }
    __syncthreads();   // stage reused by next tile
  }
}

// ======================= Fused kernel =====================================
__global__ __launch_bounds__(256, 4) void k_all(
    const float* __restrict__ pos, const float* __restrict__ ref_poc,
    const int* __restrict__ rec_idx, const int* __restrict__ cid,
    const int* __restrict__ poc_idx, const int* __restrict__ poc_cid,
    const int* __restrict__ ncp, const float* __restrict__ box,
    const float* __restrict__ kp, int R, int P, int N,
    uint32* __restrict__ gcount, uint32* __restrict__ grecords,
    uchar* __restrict__ inv8, float* __restrict__ psum,
    float* __restrict__ ws, float* __restrict__ out,
    uint32* __restrict__ bar, uint32* __restrict__ okflag) {
  __shared__ ShU sh;
  __shared__ MiscSh ms;
  __shared__ int shOk;
  const int bid = blockIdx.x;
  const int gridN = gridDim.x;
  const int pbN = gridN >> 1;            // 512 pocket / 512 partition
  const int C = ncp[0];
  phaseA(pos, ref_poc, rec_idx, cid, poc_idx, poc_cid, C, R, P,
         gcount, grecords, ws, sh, ms, bid, pbN, gridN - pbN);
  bool ok = gridBar(bar, gridN, 1, &shOk);
  if (ok) {
    phaseBC(pos, gcount, grecords, N, inv8, psum, sh, ms, bid, gridN);
    ok = gridBar(bar, gridN, 2, &shOk);
  }
  if (ok) {
    phaseFZ(box, kp, C, R, ws, psum, ms, bid);
    ok = gridBar(bar, gridN, 3, &shOk);
  }
  if (ok) {
    if (bid == 0 && threadIdx.x == 0)
      __hip_atomic_store(okflag, 1u, __ATOMIC_RELEASE, __HIP_MEMORY_SCOPE_AGENT);
    phaseD(pos, inv8, N, ws, out, sh, ms, bid, gridN);
  }
}

// ======================= Guarded backup (512 blocks, proven residency) ====
__global__ __launch_bounds__(256, 4) void k_backup(
    const float* __restrict__ pos, const float* __restrict__ box,
    const float* __restrict__ kp, const int* __restrict__ ncp,
    int R, int N,
    const uint32* __restrict__ gcount, const uint32* __restrict__ grecords,
    uchar* __restrict__ inv8, float* __restrict__ psum,
    float* __restrict__ ws, float* __restrict__ out,
    uint32* __restrict__ bar2, const uint32* __restrict__ okflag) {
  if (__hip_atomic_load(okflag, __ATOMIC_ACQUIRE, __HIP_MEMORY_SCOPE_AGENT) != 0)
    return;                              // fused path succeeded: no-op
  __shared__ ShU sh;
  __shared__ MiscSh ms;
  __shared__ int shOk;
  const int bid = blockIdx.x;
  const int gridN = gridDim.x;
  phaseBC(pos, gcount, grecords, N, inv8, psum, sh, ms, bid, gridN);
  gridBar(bar2, gridN, 1, &shOk);        // best effort: 512 proven resident
  phaseFZ(box, kp, ncp[0], R, ws, psum, ms, bid);
  gridBar(bar2, gridN, 2, &shOk);
  phaseD(pos, inv8, N, ws, out, sh, ms, bid, gridN);
}

extern "C" void kernel_launch(void* const* d_in, const int* in_sizes, int n_in,
                              void* d_out, int out_size, void* d_ws, size_t ws_size,
                              hipStream_t stream) {
  const float* pos     = (const float*)d_in[0];
  const float* box     = (const float*)d_in[1];
  const float* ref_poc = (const float*)d_in[2];
  const float* kp      = (const float*)d_in[3];
  const int* rec_idx   = (const int*)d_in[4];
  const int* poc_idx   = (const int*)d_in[5];
  const int* cid       = (const int*)d_in[6];
  const int* poc_cid   = (const int*)d_in[7];
  const int* ncp       = (const int*)d_in[8];
  float* out = (float*)d_out;
  float* ws  = (float*)d_ws;
  uint32* bar      = (uint32*)((char*)d_ws + BAR_OFF);
  uint32* bar2     = (uint32*)((char*)d_ws + BAR2_OFF);
  uint32* okflag   = (uint32*)((char*)d_ws + OK_OFF);
  uint32* gcount   = (uint32*)((char*)d_ws + GCOUNT_OFF);
  float*  psum     = (float*)((char*)d_ws + PSUM_OFF);
  uint32* grecords = (uint32*)((char*)d_ws + REC_OFF);
  uchar*  inv8     = (uchar*)d_ws + INV8_OFF;

  const int N = in_sizes[0] / 3;   // 8M atoms
  const int R = in_sizes[4];       // 2M rec
  const int P = in_sizes[5];       // 500K pocket

  hipMemsetAsync(d_ws, 0, 8192, stream);

  k_all<<<GRID_ALL, 256, 0, stream>>>(
      pos, ref_poc, rec_idx, cid, poc_idx, poc_cid, ncp, box, kp,
      R, P, N, gcount, grecords, inv8, psum, ws, out, bar, okflag);
  k_backup<<<GRID_BK, 256, 0, stream>>>(
      pos, box, kp, ncp, R, N, gcount, grecords, inv8, psum, ws, out,
      bar2, okflag);
}

// Round 5
// 874.794 us; speedup vs baseline: 1.1812x; 1.1812x over previous
//
#include <hip/hip_runtime.h>

// ---------------------------------------------------------------------------
// AlignmentForce — single-kernel task-queue pipeline (residency-oblivious).
//
// Round-4 post-mortem: grid-1024 barrier fusion did NOT co-reside in timed
// runs (occupancy query's 2 blocks/CU was right); blocks burned the spin
// timeout twice + backup -> 1033 us. Round 3 proved 512 blocks co-reside and
// the fence/atomic protocol works. Lesson: fusion must not REQUIRE residency.
//
// This round: global work queue. One cursor serves dependency-ordered task
// ranges [pocket 512][partition-chunks][BC buckets 512][FZ 1]; a second
// batched cursor serves D tiles. A task is poppable only after all its
// prerequisites are CLAIMED by running (resident) blocks, so guard spins
// (on done-counters, acquire/fence protocol proven in round 3) always wait
// on work that is guaranteed to finish: deadlock-free at ANY residency.
//   residency  512: phases serialize ~= round-0 GPU time, minus 3 dispatch
//                   boundaries (~100 us of round-0 overhead).
//   residency 1024: pocket || partition overlap, BC/D at full width.
// Phase bodies are byte-identical to the proven round-0 kernels.
//
// Algebra (validated prior session):
//   F_sum  = sum_c S_Fc,  S_Fc = -2k(Sp_c + n_c*bt_c - Sref_c)
//   T_sum  = 2k*Xpr - 2k*sum_c cross(Sp_c,bt_c) + sum_c cross(bt_c,S_Fc)
//            - cross(o, F_sum),  Xpr = sum_j cross(p_rec_j, ref_j)
//   o      = (pos_sum + sum_c nrec_c*bt_c) / R
//
// ws layout:
//   floats [0..47] bt[16][3], [48..50] o, [52..54] F_mean, [56..58] T_mean
//   floats [64.. ] acc: [0..2] pos_sum, [3..18] nrec[16], [19..21] Xpr,
//                       [22+c*10+{Sg3,Sref3,Sp3,npoc}]
//   bytes [3584] cursor, [3712] d_cursor (separate cache lines)
//   bytes [3840/3848/3856/3864] pocket_done / part_done / bc_done / fz_done
//   bytes [4096..6143]  gcount[512] (uint)
//   bytes [8192..+10.49M) grecords[512][5120] (uint)
//   bytes [INV8_OFF..+N) inv8 chain map (fully written by BC tasks)
// Only bytes [0,8192) are memset to 0 per launch.
// ---------------------------------------------------------------------------

typedef unsigned int uint32;
typedef unsigned char uchar;

#define MAXC 16
#define W_BT 0
#define W_O 48
#define W_FM 52
#define W_TM 56
#define W_ACC 64

#define CUR_OFF   3584
#define DCUR_OFF  3712
#define POCD_OFF  3840
#define PARTD_OFF 3848
#define BCD_OFF   3856
#define FZD_OFF   3864

#define GCOUNT_OFF 4096
#define REC_OFF 8192
#define NB 512
#define BSH 14
#define BUCKET_ATOMS (1 << BSH)          // 16384
#define CAP 5120                          // mean 3906, ~22 sigma headroom
#define INV8_OFF (REC_OFF + NB * CAP * 4)

#define TPOC 512                          // pocket tasks
#define K1_KPT 16
#define K1_CHUNK (256 * K1_KPT)           // 4096 records per partition task
#define DBATCH 4                          // D tiles per claim
#define GRID 1024

#define SPIN_MAX (1 << 20)                // ~0.2 s cap: terminate, never hang

struct PartSh { uint32 hist[NB]; uint32 curs[NB]; uint32 base[NB]; };   // 6 KB
struct PocSh  { float red[4][43]; float accL[3 + MAXC * 10]; };
struct MapSh  { uchar map_[BUCKET_ATOMS]; };                            // 16 KB
struct StageSh{ float stage[3328]; };                                   // 13.3 KB
union ShU { PartSh part; PocSh poc; MapSh map; StageSh st; };
struct MiscSh { float red7[4][7]; float sc[64]; float cnt16[MAXC]; float tot[192]; };

__device__ inline float waveSum(float v) {
#pragma unroll
  for (int off = 32; off > 0; off >>= 1) v += __shfl_down(v, off, 64);
  return v;
}

__device__ inline uint32 aload(const uint32* p) {
  return __hip_atomic_load(p, __ATOMIC_ACQUIRE, __HIP_MEMORY_SCOPE_AGENT);
}
__device__ inline void adone(uint32* p) {
  __threadfence();
  __hip_atomic_fetch_add(p, 1u, __ATOMIC_RELEASE, __HIP_MEMORY_SCOPE_AGENT);
}

__global__ __launch_bounds__(256, 4) void k_all(
    const float* __restrict__ pos, const float* __restrict__ ref_poc,
    const int* __restrict__ rec_idx, const int* __restrict__ cid,
    const int* __restrict__ poc_idx, const int* __restrict__ poc_cid,
    const int* __restrict__ ncp, const float* __restrict__ box,
    const float* __restrict__ kp, int R, int P, int N,
    uint32* __restrict__ gcount, uint32* __restrict__ grecords,
    uchar* __restrict__ inv8, float* __restrict__ ws,
    float* __restrict__ out,
    uint32* __restrict__ qcur, uint32* __restrict__ dcur,
    uint32* __restrict__ pocd, uint32* __restrict__ partd,
    uint32* __restrict__ bcd, uint32* __restrict__ fzd) {
  __shared__ ShU sh;
  __shared__ MiscSh ms;
  __shared__ int shTask;
  __shared__ int shSeen;
  const int tid = threadIdx.x;
  const int C = ncp[0];
  const int NCHUNK = (R + K1_CHUNK - 1) / K1_CHUNK;
  const int T_PART_END = TPOC + NCHUNK;
  const int T_BC_END = T_PART_END + NB;
  const int T_FZ_END = T_BC_END + 1;
  const int ntiles = (N + 1023) >> 10;
  if (tid == 0) shSeen = 0;

  // ======================= main dependency-ordered queue ==================
  for (;;) {
    __syncthreads();                       // protect sh/ms/shTask reuse
    if (tid == 0) shTask = (int)atomicAdd(qcur, 1u);
    __syncthreads();
    const int t = shTask;
    if (t >= T_FZ_END) break;

    if (t < TPOC) {
      // ------------- pocket task t (round-0 body, bid=t, PB=512) ---------
      const int gsz = TPOC * 256;
      if (C <= 4) {
        float vals[43];  // [0..2] Xpr, [3+cc*10+q] {Sg3,Sref3,Sp3,npoc}
#pragma unroll
        for (int v = 0; v < 43; ++v) vals[v] = 0.f;
        for (int rb = t * 256 + tid; rb < P; rb += 4 * gsz) {
          int rr[4], i2[4], c2[4], ri[4];
          float g[4][3], p[4][3], rf[4][3];
#pragma unroll
          for (int q = 0; q < 4; ++q) {
            int r = rb + q * gsz;
            rr[q] = (r < P) ? r : -1;
          }
#pragma unroll
          for (int q = 0; q < 4; ++q) {     // wave 1: independent loads
            int r = (rr[q] < 0) ? 0 : rr[q];
            i2[q] = poc_idx[r];
            c2[q] = poc_cid[r];
          }
#pragma unroll
          for (int q = 0; q < 4; ++q) {     // wave 2: dependent on i2
            ri[q] = rec_idx[i2[q]];
            g[q][0] = pos[3 * i2[q] + 0];   // faithful reference bug:
            g[q][1] = pos[3 * i2[q] + 1];   // global positions @ rec-space idx
            g[q][2] = pos[3 * i2[q] + 2];
          }
#pragma unroll
          for (int q = 0; q < 4; ++q) {     // wave 3: dependent on ri
            int r = (rr[q] < 0) ? 0 : rr[q];
            p[q][0] = pos[3 * ri[q] + 0];
            p[q][1] = pos[3 * ri[q] + 1];
            p[q][2] = pos[3 * ri[q] + 2];
            rf[q][0] = ref_poc[3 * r + 0];
            rf[q][1] = ref_poc[3 * r + 1];
            rf[q][2] = ref_poc[3 * r + 2];
          }
#pragma unroll
          for (int q = 0; q < 4; ++q) {
            if (rr[q] >= 0) {
              vals[0] += p[q][1] * rf[q][2] - p[q][2] * rf[q][1];
              vals[1] += p[q][2] * rf[q][0] - p[q][0] * rf[q][2];
              vals[2] += p[q][0] * rf[q][1] - p[q][1] * rf[q][0];
#pragma unroll
              for (int cc = 0; cc < 4; ++cc) {
                bool m = (c2[q] == cc);
                float* a = &vals[3 + cc * 10];
                a[0] += m ? g[q][0] : 0.f; a[1] += m ? g[q][1] : 0.f;
                a[2] += m ? g[q][2] : 0.f;
                a[3] += m ? rf[q][0] : 0.f; a[4] += m ? rf[q][1] : 0.f;
                a[5] += m ? rf[q][2] : 0.f;
                a[6] += m ? p[q][0] : 0.f; a[7] += m ? p[q][1] : 0.f;
                a[8] += m ? p[q][2] : 0.f;
                a[9] += m ? 1.f : 0.f;
              }
            }
          }
        }
        const int wid = tid >> 6;
#pragma unroll
        for (int v = 0; v < 43; ++v) {
          float s = waveSum(vals[v]);
          if ((tid & 63) == 0) sh.poc.red[wid][v] = s;
        }
        __syncthreads();
        for (int s = tid; s < 43; s += 256)
          atomicAdd(&ws[W_ACC + 19 + s], sh.poc.red[0][s] + sh.poc.red[1][s] +
                                         sh.poc.red[2][s] + sh.poc.red[3][s]);
      } else {
        // generic fallback 5 <= C <= 16 (correctness over speed)
        float* accL = sh.poc.accL;
        for (int s = tid; s < 3 + MAXC * 10; s += 256) accL[s] = 0.f;
        __syncthreads();
        for (int r = t * 256 + tid; r < P; r += TPOC * 256) {
          int i2 = poc_idx[r];
          int c2 = poc_cid[r];
          int ri = rec_idx[i2];
          float gx = pos[3 * i2 + 0], gy = pos[3 * i2 + 1], gz = pos[3 * i2 + 2];
          float px = pos[3 * ri + 0], py = pos[3 * ri + 1], pz = pos[3 * ri + 2];
          float rx = ref_poc[3 * r + 0], ry = ref_poc[3 * r + 1], rz = ref_poc[3 * r + 2];
          atomicAdd(&accL[0], py * rz - pz * ry);
          atomicAdd(&accL[1], pz * rx - px * rz);
          atomicAdd(&accL[2], px * ry - py * rx);
          float* a = &accL[3 + c2 * 10];
          atomicAdd(&a[0], gx); atomicAdd(&a[1], gy); atomicAdd(&a[2], gz);
          atomicAdd(&a[3], rx); atomicAdd(&a[4], ry); atomicAdd(&a[5], rz);
          atomicAdd(&a[6], px); atomicAdd(&a[7], py); atomicAdd(&a[8], pz);
          atomicAdd(&a[9], 1.f);
        }
        __syncthreads();
        for (int s = tid; s < 3 + MAXC * 10; s += 256)
          if (accL[s] != 0.f) atomicAdd(&ws[W_ACC + 19 + s], accL[s]);
      }
      if (tid == 0) adone(pocd);

    } else if (t < T_PART_END) {
      // ------------- partition task: chunk j (round-0 body) --------------
      const int j = t - TPOC;
      const int r0 = j * K1_CHUNK;
      int cnt = R - r0; if (cnt > K1_CHUNK) cnt = K1_CHUNK;
      uint32* hist = sh.part.hist;
      uint32* curs = sh.part.curs;
      uint32* base = sh.part.base;
      for (int s = tid; s < NB; s += 256) { hist[s] = 0u; curs[s] = 0u; }
      __syncthreads();
      uint32 enc[K1_KPT];
#pragma unroll
      for (int jj = 0; jj < K1_KPT; ++jj) {
        int s = tid + jj * 256;
        uint32 e = 0xFFFFFFFFu;
        if (s < cnt) {
          uint32 idx = (uint32)rec_idx[r0 + s];
          uint32 c = (uint32)cid[r0 + s] & 255u;
          e = (idx << 8) | c;
          atomicAdd(&hist[idx >> BSH], 1u);
        }
        enc[jj] = e;
      }
      __syncthreads();
      for (int s = tid; s < NB; s += 256) {
        uint32 h = hist[s];
        base[s] = h ? atomicAdd(&gcount[s], h) : 0u;
      }
      __syncthreads();
#pragma unroll
      for (int jj = 0; jj < K1_KPT; ++jj) {
        uint32 e = enc[jj];
        if (e != 0xFFFFFFFFu) {
          uint32 b = e >> (8 + BSH);
          uint32 slot = base[b] + atomicAdd(&curs[b], 1u);
          if (slot < CAP) grecords[b * CAP + slot] = e;
        }
      }
      if (tid == 0) adone(partd);

    } else if (t < T_BC_END) {
      // ------------- BC bucket task (round-0 k_bucket_build body) --------
      // Guard: all partition tasks are claimed (queue order) and running ->
      // spin is deadlock-free at any residency.
      if (!(shSeen & 1)) {
        if (tid == 0) {
          for (int it = 0; it < SPIN_MAX; ++it) {
            if (aload(partd) >= (uint32)NCHUNK) break;
            __builtin_amdgcn_s_sleep(2);
          }
          shSeen |= 1;
        }
        __syncthreads();
        __threadfence();
      }
      const int b = t - T_PART_END;
      const int a0 = b << BSH;
      if (a0 < N) {
        int natoms = N - a0; if (natoms > BUCKET_ATOMS) natoms = BUCKET_ATOMS;
        uchar* map_ = sh.map.map_;
        uint4* m16 = (uint4*)map_;
        uint4 ff; ff.x = ff.y = ff.z = ff.w = 0xFFFFFFFFu;
        for (int s = tid; s < BUCKET_ATOMS / 16; s += 256) m16[s] = ff;
        if (C > 4) for (int s = tid; s < MAXC; s += 256) ms.cnt16[s] = 0.f;
        __syncthreads();
        int n = (int)gcount[b]; if (n > CAP) n = CAP;
        float c0 = 0.f, c1 = 0.f, c2 = 0.f, c3 = 0.f;
        for (int s = tid; s < n; s += 256) {
          uint32 e = grecords[b * CAP + s];
          uint32 ia = (e >> 8) & (BUCKET_ATOMS - 1);
          uint32 c = e & 255u;
          map_[ia] = (uchar)c;
          if (C <= 4) {
            c0 += (c == 0u) ? 1.f : 0.f;
            c1 += (c == 1u) ? 1.f : 0.f;
            c2 += (c == 2u) ? 1.f : 0.f;
            c3 += (c == 3u) ? 1.f : 0.f;
          } else {
            atomicAdd(&ms.cnt16[c], 1.f);
          }
        }
        __syncthreads();
        uchar* dst = inv8 + a0;
        if (natoms == BUCKET_ATOMS) {
          uint4* d16 = (uint4*)dst;
          for (int s = tid; s < BUCKET_ATOMS / 16; s += 256) d16[s] = m16[s];
        } else {
          for (int s = tid; s < natoms; s += 256) dst[s] = map_[s];
        }
        float sx = 0.f, sy = 0.f, sz = 0.f;
        int ngf = natoms >> 2;
        const uchar4* m4 = (const uchar4*)map_;
        const float4* pos4 = (const float4*)pos;
        int g0 = a0 >> 2;
        for (int g = tid; g < ngf; g += 256) {
          float4 p0 = pos4[3 * (g0 + g) + 0];
          float4 p1 = pos4[3 * (g0 + g) + 1];
          float4 p2 = pos4[3 * (g0 + g) + 2];
          uchar4 m = m4[g];
          if (m.x != 255) { sx += p0.x; sy += p0.y; sz += p0.z; }
          if (m.y != 255) { sx += p0.w; sy += p1.x; sz += p1.y; }
          if (m.z != 255) { sx += p1.z; sy += p1.w; sz += p2.x; }
          if (m.w != 255) { sx += p2.y; sy += p2.z; sz += p2.w; }
        }
        int tb = natoms & 3;
        if (tid < tb) {
          int a = a0 + (ngf << 2) + tid;
          const float* pf = (const float*)pos4;
          if (map_[(ngf << 2) + tid] != 255) {
            sx += pf[3 * a]; sy += pf[3 * a + 1]; sz += pf[3 * a + 2];
          }
        }
        float vv[7] = {sx, sy, sz, c0, c1, c2, c3};
        const int wid = tid >> 6;
#pragma unroll
        for (int v = 0; v < 7; ++v) {
          float s = waveSum(vv[v]);
          if ((tid & 63) == 0) ms.red7[wid][v] = s;
        }
        __syncthreads();
        if (tid < 7) {
          float s = ms.red7[0][tid] + ms.red7[1][tid] +
                    ms.red7[2][tid] + ms.red7[3][tid];
          atomicAdd(&ws[W_ACC + tid], s);   // [0..2] pos_sum, [3..6] nrec
        }
        if (C > 4 && tid < C) atomicAdd(&ws[W_ACC + 3 + tid], ms.cnt16[tid]);
      }
      if (tid == 0) adone(bcd);

    } else {
      // ------------- FZ task (single; round-0 k_finalize body) -----------
      if (tid == 0) {
        for (int it = 0; it < SPIN_MAX; ++it) {
          if (aload(pocd) >= (uint32)TPOC && aload(bcd) >= (uint32)NB) break;
          __builtin_amdgcn_s_sleep(2);
        }
      }
      __syncthreads();
      __threadfence();
      for (int s = tid; s < 192; s += 256) ms.tot[s] = ws[W_ACC + s];
      __syncthreads();
      if (tid == 0) {
        float* tot = ms.tot;
        const float kk = kp[0];
        const float Rf = (float)R;
        const float* xp = &tot[19];
        float inv0 = 1.f / box[0], inv1 = 1.f / box[4], inv2 = 1.f / box[8];
        float ox = tot[0], oy = tot[1], oz = tot[2];
        float Fx = 0, Fy = 0, Fz = 0;
        float T1x = 0, T1y = 0, T1z = 0, T2x = 0, T2y = 0, T2z = 0;
        for (int c = 0; c < C; ++c) {
          float nrec = tot[3 + c];
          const float* a = &tot[22 + c * 10];
          float np = a[9];
          float invn = 1.f / np;
          float pcx = a[0] * invn, pcy = a[1] * invn, pcz = a[2] * invn;
          float rcx = a[3] * invn, rcy = a[4] * invn, rcz = a[5] * invn;
          float dx = rcx - pcx, dy = rcy - pcy, dz = rcz - pcz;
          float s3 = rintf(dz * inv2);
          dx -= s3 * box[6]; dy -= s3 * box[7]; dz -= s3 * box[8];
          float s2 = rintf(dy * inv1);
          dx -= s2 * box[3]; dy -= s2 * box[4]; dz -= s2 * box[5];
          float s1 = rintf(dx * inv0);
          float btx = s1 * box[0] + s2 * box[3] + s3 * box[6];
          float bty = s1 * box[1] + s2 * box[4] + s3 * box[7];
          float btz = s1 * box[2] + s2 * box[5] + s3 * box[8];
          ws[W_BT + c * 3 + 0] = btx;
          ws[W_BT + c * 3 + 1] = bty;
          ws[W_BT + c * 3 + 2] = btz;
          ox += nrec * btx; oy += nrec * bty; oz += nrec * btz;
          float SFx = -2.f * kk * (a[6] + np * btx - a[3]);
          float SFy = -2.f * kk * (a[7] + np * bty - a[4]);
          float SFz = -2.f * kk * (a[8] + np * btz - a[5]);
          Fx += SFx; Fy += SFy; Fz += SFz;
          T1x += a[7] * btz - a[8] * bty;
          T1y += a[8] * btx - a[6] * btz;
          T1z += a[6] * bty - a[7] * btx;
          T2x += bty * SFz - btz * SFy;
          T2y += btz * SFx - btx * SFz;
          T2z += btx * SFy - bty * SFx;
        }
        ox /= Rf; oy /= Rf; oz /= Rf;
        float Tx = 2.f * kk * xp[0] - 2.f * kk * T1x + T2x - (oy * Fz - oz * Fy);
        float Ty = 2.f * kk * xp[1] - 2.f * kk * T1y + T2y - (oz * Fx - ox * Fz);
        float Tz = 2.f * kk * xp[2] - 2.f * kk * T1z + T2z - (ox * Fy - oy * Fx);
        ws[W_O + 0] = ox; ws[W_O + 1] = oy; ws[W_O + 2] = oz;
        ws[W_FM + 0] = Fx / Rf; ws[W_FM + 1] = Fy / Rf; ws[W_FM + 2] = Fz / Rf;
        ws[W_TM + 0] = Tx / Rf; ws[W_TM + 1] = Ty / Rf; ws[W_TM + 2] = Tz / Rf;
        adone(fzd);
      }
    }
  }

  // ======================= D mode: batched tile queue =====================
  // FZ was claimed before any block reaches here (queue order) -> safe spin.
  if (tid == 0) {
    for (int it = 0; it < SPIN_MAX; ++it) {
      if (aload(fzd) >= 1u) break;
      __builtin_amdgcn_s_sleep(2);
    }
  }
  __syncthreads();
  __threadfence();
  if (tid < 64) ms.sc[tid] = ws[tid];
  __syncthreads();
  float* sc = ms.sc;
  const float ox = sc[W_O + 0], oy = sc[W_O + 1], oz = sc[W_O + 2];
  const float fmx = sc[W_FM + 0], fmy = sc[W_FM + 1], fmz = sc[W_FM + 2];
  const float tmx = sc[W_TM + 0], tmy = sc[W_TM + 1], tmz = sc[W_TM + 2];

  for (;;) {
    if (tid == 0) shTask = (int)atomicAdd(dcur, (uint32)DBATCH);
    __syncthreads();
    const int tb = shTask;
    if (tb >= ntiles) break;
    const int te = (tb + DBATCH < ntiles) ? (tb + DBATCH) : ntiles;
    for (int tile = tb; tile < te; ++tile) {
      // round-0 k_final_dense body. stage idx = k + k/12 (odd stride 13 per
      // owner => conflict-free). Writes EVERY element (d_out is poisoned).
      const int t0 = tile << 10;
      int nat = N - t0; if (nat > 1024) nat = 1024;
      const int nfl = nat * 3;
      float* stage = sh.st.stage;

      if (nat == 1024) {
        const float4* src4 = (const float4*)(pos + 3 * t0);
#pragma unroll
        for (int kk = 0; kk < 3; ++kk) {
          int v4 = tid + kk * 256;        // 0..767
          float4 p = src4[v4];
          int idx = 4 * v4 + v4 / 3;      // = g + g/12, g = 4*v4
          stage[idx + 0] = p.x; stage[idx + 1] = p.y;
          stage[idx + 2] = p.z; stage[idx + 3] = p.w;
        }
      } else {
        for (int k = tid; k < nfl; k += 256)
          stage[k + (int)((unsigned)k / 12u)] = pos[3 * t0 + k];
      }
      __syncthreads();

      uchar mc[4];
      if (nat == 1024) {
        uchar4 m = ((const uchar4*)(inv8 + t0))[tid];
        mc[0] = m.x; mc[1] = m.y; mc[2] = m.z; mc[3] = m.w;
      } else {
#pragma unroll
        for (int q = 0; q < 4; ++q) {
          int la = 4 * tid + q;
          mc[q] = (la < nat) ? inv8[t0 + la] : (uchar)255;
        }
      }
#pragma unroll
      for (int q = 0; q < 4; ++q) {
        int la = 4 * tid + q;
        if (la < nat) {
          float* s = &stage[13 * tid + 3 * q];
          float fx = 0.f, fy = 0.f, fz = 0.f;
          int c = mc[q];
          if (c != 255) {
            float cx = s[0] + sc[W_BT + 3 * c + 0] - ox;
            float cy = s[1] + sc[W_BT + 3 * c + 1] - oy;
            float cz = s[2] + sc[W_BT + 3 * c + 2] - oz;
            float inv = 1.f / (cx * cx + cy * cy + cz * cz);
            fx = fmx + (tmy * cz - tmz * cy) * inv;
            fy = fmy + (tmz * cx - tmx * cz) * inv;
            fz = fmz + (tmx * cy - tmy * cx) * inv;
          }
          s[0] = fx; s[1] = fy; s[2] = fz;   // own slots only
        }
      }
      __syncthreads();

      if (tile == 0 && tid == 0) out[0] = 0.f;  // energy scalar
      float* ob = out + 1 + 3 * t0;
      if (nat == 1024) {
#pragma unroll
        for (int kk = 0; kk < 3; ++kk) {
          int j = tid + kk * 256;
          if (j < 767) {
            int k = 3 + 4 * j;
            float4 v;
            v.x = stage[k + k / 12];
            v.y = stage[(k + 1) + (k + 1) / 12];
            v.z = stage[(k + 2) + (k + 2) / 12];
            v.w = stage[(k + 3) + (k + 3) / 12];
            *(float4*)(ob + k) = v;
          }
        }
        if (tid < 3) ob[tid] = stage[tid];               // k=0,1,2
        if (tid == 3) ob[3071] = stage[3071 + 3071 / 12];
      } else {
        for (int k = tid; k < nfl; k += 256)
          ob[k] = stage[k + (int)((unsigned)k / 12u)];
      }
      __syncthreads();   // stage reused by next tile
    }
  }
}

extern "C" void kernel_launch(void* const* d_in, const int* in_sizes, int n_in,
                              void* d_out, int out_size, void* d_ws, size_t ws_size,
                              hipStream_t stream) {
  const float* pos     = (const float*)d_in[0];
  const float* box     = (const float*)d_in[1];
  const float* ref_poc = (const float*)d_in[2];
  const float* kp      = (const float*)d_in[3];
  const int* rec_idx   = (const int*)d_in[4];
  const int* poc_idx   = (const int*)d_in[5];
  const int* cid       = (const int*)d_in[6];
  const int* poc_cid   = (const int*)d_in[7];
  const int* ncp       = (const int*)d_in[8];
  float* out = (float*)d_out;
  float* ws  = (float*)d_ws;
  uint32* qcur     = (uint32*)((char*)d_ws + CUR_OFF);
  uint32* dcur     = (uint32*)((char*)d_ws + DCUR_OFF);
  uint32* pocd     = (uint32*)((char*)d_ws + POCD_OFF);
  uint32* partd    = (uint32*)((char*)d_ws + PARTD_OFF);
  uint32* bcd      = (uint32*)((char*)d_ws + BCD_OFF);
  uint32* fzd      = (uint32*)((char*)d_ws + FZD_OFF);
  uint32* gcount   = (uint32*)((char*)d_ws + GCOUNT_OFF);
  uint32* grecords = (uint32*)((char*)d_ws + REC_OFF);
  uchar*  inv8     = (uchar*)d_ws + INV8_OFF;

  const int N = in_sizes[0] / 3;   // 8M atoms
  const int R = in_sizes[4];       // 2M rec
  const int P = in_sizes[5];       // 500K pocket

  hipMemsetAsync(d_ws, 0, 8192, stream);

  k_all<<<GRID, 256, 0, stream>>>(
      pos, ref_poc, rec_idx, cid, poc_idx, poc_cid, ncp, box, kp,
      R, P, N, gcount, grecords, inv8, ws, out,
      qcur, dcur, pocd, partd, bcd, fzd);
}

// Round 6
// 270.216 us; speedup vs baseline: 3.8239x; 3.2374x over previous
//
#include <hip/hip_runtime.h>

// ---------------------------------------------------------------------------
// AlignmentForce — re-pipelined 3-kernel schedule (no intra-kernel sync).
//
// Rounds 2-5 post-mortem: every intra-kernel grid-sync mechanism (cooperative
// launch, DIY barrier, task queue) ran 650-1050 us real with ~2% VALUBusy —
// abandoned. Re-derivation of round-0: harness overhead (~80-100 us) is fixed
// per launch SEQUENCE, not per dispatch; the lever is overlapping the
// dependency chain, using dispatch boundaries as the only sync.
//
// Chain: partition -> BC -> FZ -> D;  pocket independent until FZ.
//   K1 k_partition: partition alone (~20 us).
//   K2 k_gather   : pocket (512 blocks) CONCURRENT WITH BC (512 blocks),
//                   bid-interleaved (even=pocket, odd=bucket) so both roles
//                   are resident at any residency. Pocket is latency-bound
//                   (~2 TB/s); BC's dense stream rides the spare bandwidth.
//   K3 k_finout   : FZ computed REDUNDANTLY per block (192-float acc load +
//                   ~300 scalar ops, hidden under pos staging) + streaming
//                   output. Removes the finalize dispatch with zero sync.
//
// Algebra (validated prior session):
//   F_sum  = sum_c S_Fc,  S_Fc = -2k(Sp_c + n_c*bt_c - Sref_c)
//   T_sum  = 2k*Xpr - 2k*sum_c cross(Sp_c,bt_c) + sum_c cross(bt_c,S_Fc)
//            - cross(o, F_sum),  Xpr = sum_j cross(p_rec_j, ref_j)
//   o      = (pos_sum + sum_c nrec_c*bt_c) / R
//
// ws layout:
//   floats [64..255] acc: [0..2] pos_sum, [3..18] nrec[16], [19..21] Xpr,
//                         [22+c*10+{Sg3,Sref3,Sp3,npoc}]
//   bytes [4096..6143]  gcount[512] (uint)
//   bytes [8192..+10.49M) grecords[512][5120] (uint)
//   bytes [INV8_OFF..+N) inv8 chain map (fully written by K2 BC blocks)
// Only bytes [0,8192) are memset to 0 per launch.
// ---------------------------------------------------------------------------

typedef unsigned int uint32;
typedef unsigned char uchar;

#define MAXC 16
#define W_BT 0
#define W_O 48
#define W_FM 52
#define W_TM 56
#define W_ACC 64

#define GCOUNT_OFF 4096
#define REC_OFF 8192
#define NB 512
#define BSH 14
#define BUCKET_ATOMS (1 << BSH)          // 16384
#define CAP 5120                          // mean 3906, ~22 sigma headroom
#define INV8_OFF (REC_OFF + NB * CAP * 4)

#define PB 512                            // pocket tasks in K2
#define K1_KPT 16
#define K1_CHUNK (256 * K1_KPT)           // 4096 records per partition block

struct PocSh  { float accL[3 + MAXC * 10]; };
struct MapSh  { uchar map_[BUCKET_ATOMS]; };                            // 16 KB
union ShU { PocSh poc; MapSh map; };

__device__ inline float waveSum(float v) {
#pragma unroll
  for (int off = 32; off > 0; off >>= 1) v += __shfl_down(v, off, 64);
  return v;
}

// ======================= K1: partition =====================================
__global__ __launch_bounds__(256) void k_partition(
    const int* __restrict__ rec_idx, const int* __restrict__ cid,
    int R, uint32* __restrict__ gcount, uint32* __restrict__ grecords) {
  __shared__ uint32 hist[NB];
  __shared__ uint32 curs[NB];
  __shared__ uint32 base[NB];
  const int tid = threadIdx.x;
  const int r0 = blockIdx.x * K1_CHUNK;
  int cnt = R - r0; if (cnt > K1_CHUNK) cnt = K1_CHUNK;
  for (int t = tid; t < NB; t += 256) { hist[t] = 0u; curs[t] = 0u; }
  __syncthreads();
  uint32 enc[K1_KPT];
#pragma unroll
  for (int j = 0; j < K1_KPT; ++j) {
    int t = tid + j * 256;
    uint32 e = 0xFFFFFFFFu;
    if (t < cnt) {
      uint32 idx = (uint32)rec_idx[r0 + t];
      uint32 c = (uint32)cid[r0 + t] & 255u;
      e = (idx << 8) | c;
      atomicAdd(&hist[idx >> BSH], 1u);
    }
    enc[j] = e;
  }
  __syncthreads();
  for (int t = tid; t < NB; t += 256) {
    uint32 h = hist[t];
    base[t] = h ? atomicAdd(&gcount[t], h) : 0u;
  }
  __syncthreads();
#pragma unroll
  for (int j = 0; j < K1_KPT; ++j) {
    uint32 e = enc[j];
    if (e != 0xFFFFFFFFu) {
      uint32 b = e >> (8 + BSH);
      uint32 slot = base[b] + atomicAdd(&curs[b], 1u);
      if (slot < CAP) grecords[b * CAP + slot] = e;
    }
  }
}

// ======================= K2: pocket (even bids) || BC (odd bids) ===========
__global__ __launch_bounds__(256) void k_gather(
    const float* __restrict__ pos, const float* __restrict__ ref_poc,
    const int* __restrict__ rec_idx,
    const int* __restrict__ poc_idx, const int* __restrict__ poc_cid,
    const int* __restrict__ ncp, int P, int N,
    const uint32* __restrict__ gcount, const uint32* __restrict__ grecords,
    uchar* __restrict__ inv8, float* __restrict__ ws) {
  const int tid = threadIdx.x;
  const int bid = blockIdx.x;
  const int C = ncp[0];
  __shared__ ShU sh;
  __shared__ float red[4][43];
  __shared__ float cnt16[MAXC];

  if ((bid & 1) == 0) {
    // ---------------- pocket reductions (4-way batched gathers) -----------
    const int pt = bid >> 1;              // 0..511
    const int gsz = PB * 256;
    if (C <= 4) {
      float vals[43];  // [0..2] Xpr, [3+cc*10+q] {Sg3,Sref3,Sp3,npoc}
#pragma unroll
      for (int v = 0; v < 43; ++v) vals[v] = 0.f;
      for (int rb = pt * 256 + tid; rb < P; rb += 4 * gsz) {
        int rr[4], i2[4], c2[4], ri[4];
        float g[4][3], p[4][3], rf[4][3];
#pragma unroll
        for (int q = 0; q < 4; ++q) {
          int r = rb + q * gsz;
          rr[q] = (r < P) ? r : -1;
        }
#pragma unroll
        for (int q = 0; q < 4; ++q) {       // wave 1: independent loads
          int r = (rr[q] < 0) ? 0 : rr[q];
          i2[q] = poc_idx[r];
          c2[q] = poc_cid[r];
        }
#pragma unroll
        for (int q = 0; q < 4; ++q) {       // wave 2: dependent on i2
          ri[q] = rec_idx[i2[q]];
          g[q][0] = pos[3 * i2[q] + 0];     // faithful reference bug:
          g[q][1] = pos[3 * i2[q] + 1];     // global positions @ rec-space idx
          g[q][2] = pos[3 * i2[q] + 2];
        }
#pragma unroll
        for (int q = 0; q < 4; ++q) {       // wave 3: dependent on ri
          int r = (rr[q] < 0) ? 0 : rr[q];
          p[q][0] = pos[3 * ri[q] + 0];
          p[q][1] = pos[3 * ri[q] + 1];
          p[q][2] = pos[3 * ri[q] + 2];
          rf[q][0] = ref_poc[3 * r + 0];
          rf[q][1] = ref_poc[3 * r + 1];
          rf[q][2] = ref_poc[3 * r + 2];
        }
#pragma unroll
        for (int q = 0; q < 4; ++q) {
          if (rr[q] >= 0) {
            vals[0] += p[q][1] * rf[q][2] - p[q][2] * rf[q][1];
            vals[1] += p[q][2] * rf[q][0] - p[q][0] * rf[q][2];
            vals[2] += p[q][0] * rf[q][1] - p[q][1] * rf[q][0];
#pragma unroll
            for (int cc = 0; cc < 4; ++cc) {
              bool m = (c2[q] == cc);
              float* a = &vals[3 + cc * 10];
              a[0] += m ? g[q][0] : 0.f; a[1] += m ? g[q][1] : 0.f;
              a[2] += m ? g[q][2] : 0.f;
              a[3] += m ? rf[q][0] : 0.f; a[4] += m ? rf[q][1] : 0.f;
              a[5] += m ? rf[q][2] : 0.f;
              a[6] += m ? p[q][0] : 0.f; a[7] += m ? p[q][1] : 0.f;
              a[8] += m ? p[q][2] : 0.f;
              a[9] += m ? 1.f : 0.f;
            }
          }
        }
      }
      const int wid = tid >> 6;
#pragma unroll
      for (int v = 0; v < 43; ++v) {
        float s = waveSum(vals[v]);
        if ((tid & 63) == 0) red[wid][v] = s;
      }
      __syncthreads();
      for (int t = tid; t < 43; t += 256)
        atomicAdd(&ws[W_ACC + 19 + t],
                  red[0][t] + red[1][t] + red[2][t] + red[3][t]);
    } else {
      // generic fallback 5 <= C <= 16 (correctness over speed)
      float* accL = sh.poc.accL;
      for (int t = tid; t < 3 + MAXC * 10; t += 256) accL[t] = 0.f;
      __syncthreads();
      for (int r = pt * 256 + tid; r < P; r += PB * 256) {
        int i2 = poc_idx[r];
        int c2 = poc_cid[r];
        int ri = rec_idx[i2];
        float gx = pos[3 * i2 + 0], gy = pos[3 * i2 + 1], gz = pos[3 * i2 + 2];
        float px = pos[3 * ri + 0], py = pos[3 * ri + 1], pz = pos[3 * ri + 2];
        float rx = ref_poc[3 * r + 0], ry = ref_poc[3 * r + 1], rz = ref_poc[3 * r + 2];
        atomicAdd(&accL[0], py * rz - pz * ry);
        atomicAdd(&accL[1], pz * rx - px * rz);
        atomicAdd(&accL[2], px * ry - py * rx);
        float* a = &accL[3 + c2 * 10];
        atomicAdd(&a[0], gx); atomicAdd(&a[1], gy); atomicAdd(&a[2], gz);
        atomicAdd(&a[3], rx); atomicAdd(&a[4], ry); atomicAdd(&a[5], rz);
        atomicAdd(&a[6], px); atomicAdd(&a[7], py); atomicAdd(&a[8], pz);
        atomicAdd(&a[9], 1.f);
      }
      __syncthreads();
      for (int t = tid; t < 3 + MAXC * 10; t += 256)
        if (accL[t] != 0.f) atomicAdd(&ws[W_ACC + 19 + t], accL[t]);
    }
  } else {
    // ---------------- BC: bucket map -> inv8 + masked pos_sum + nrec ------
    const int b = bid >> 1;               // 0..511
    const int a0 = b << BSH;
    if (a0 >= N) return;                  // uniform per block
    int natoms = N - a0; if (natoms > BUCKET_ATOMS) natoms = BUCKET_ATOMS;
    uchar* map_ = sh.map.map_;
    uint4* m16 = (uint4*)map_;
    uint4 ff; ff.x = ff.y = ff.z = ff.w = 0xFFFFFFFFu;
    for (int t = tid; t < BUCKET_ATOMS / 16; t += 256) m16[t] = ff;
    if (C > 4) for (int t = tid; t < MAXC; t += 256) cnt16[t] = 0.f;
    __syncthreads();
    int n = (int)gcount[b]; if (n > CAP) n = CAP;
    float c0 = 0.f, c1 = 0.f, c2 = 0.f, c3 = 0.f;
    for (int t = tid; t < n; t += 256) {
      uint32 e = grecords[b * CAP + t];
      uint32 ia = (e >> 8) & (BUCKET_ATOMS - 1);
      uint32 c = e & 255u;
      map_[ia] = (uchar)c;
      if (C <= 4) {
        c0 += (c == 0u) ? 1.f : 0.f;
        c1 += (c == 1u) ? 1.f : 0.f;
        c2 += (c == 2u) ? 1.f : 0.f;
        c3 += (c == 3u) ? 1.f : 0.f;
      } else {
        atomicAdd(&cnt16[c], 1.f);
      }
    }
    __syncthreads();
    uchar* dst = inv8 + a0;
    if (natoms == BUCKET_ATOMS) {
      uint4* d16 = (uint4*)dst;
      for (int t = tid; t < BUCKET_ATOMS / 16; t += 256) d16[t] = m16[t];
    } else {
      for (int t = tid; t < natoms; t += 256) dst[t] = map_[t];
    }
    float sx = 0.f, sy = 0.f, sz = 0.f;
    int ngf = natoms >> 2;
    const uchar4* m4 = (const uchar4*)map_;
    const float4* pos4 = (const float4*)pos;
    int g0 = a0 >> 2;
    for (int g = tid; g < ngf; g += 256) {
      float4 p0 = pos4[3 * (g0 + g) + 0];
      float4 p1 = pos4[3 * (g0 + g) + 1];
      float4 p2 = pos4[3 * (g0 + g) + 2];
      uchar4 m = m4[g];
      if (m.x != 255) { sx += p0.x; sy += p0.y; sz += p0.z; }
      if (m.y != 255) { sx += p0.w; sy += p1.x; sz += p1.y; }
      if (m.z != 255) { sx += p1.z; sy += p1.w; sz += p2.x; }
      if (m.w != 255) { sx += p2.y; sy += p2.z; sz += p2.w; }
    }
    int tb = natoms & 3;
    if (tid < tb) {
      int a = a0 + (ngf << 2) + tid;
      if (map_[(ngf << 2) + tid] != 255) {
        sx += pos[3 * a]; sy += pos[3 * a + 1]; sz += pos[3 * a + 2];
      }
    }
    float vv[7] = {sx, sy, sz, c0, c1, c2, c3};
    const int wid = tid >> 6;
#pragma unroll
    for (int v = 0; v < 7; ++v) {
      float s = waveSum(vv[v]);
      if ((tid & 63) == 0) red[wid][v] = s;
    }
    __syncthreads();
    if (tid < 7) {
      float s = red[0][tid] + red[1][tid] + red[2][tid] + red[3][tid];
      atomicAdd(&ws[W_ACC + tid], s);   // [0..2] pos_sum, [3..6] nrec c<4
    }
    if (C > 4 && tid < C) atomicAdd(&ws[W_ACC + 3 + tid], cnt16[tid]);
  }
}

// ======================= K3: per-block FZ + streaming output ===============
// stage idx = k + k/12 (odd stride 13 per owner => conflict-free). Global
// range of a full block starts at out-index 1+3072b (== 1 mod 4): 3 scalar
// floats, then 767 dwordx4 stores, then 1 scalar. Writes EVERY element
// (d_out is poisoned). FZ (~300 scalar ops on lane 0) is recomputed per
// block from the 192-float acc — hidden under the pos staging loads.
__global__ __launch_bounds__(256) void k_finout(
    const float* __restrict__ pos, const uchar* __restrict__ inv8,
    const float* __restrict__ box, const float* __restrict__ kp,
    const int* __restrict__ ncp, int R, int N,
    const float* __restrict__ ws, float* __restrict__ out) {
  __shared__ float stage[3328];
  __shared__ float tot[192];
  __shared__ float sc[64];
  const int tid = threadIdx.x;
  const int t0 = blockIdx.x * 1024;
  int nat = N - t0; if (nat > 1024) nat = 1024;
  const int nfl = nat * 3;

  for (int t = tid; t < 192; t += 256) tot[t] = ws[W_ACC + t];

  if (nat == 1024) {
    const float4* src4 = (const float4*)(pos + 3 * t0);
#pragma unroll
    for (int kk = 0; kk < 3; ++kk) {
      int v4 = tid + kk * 256;          // 0..767
      float4 p = src4[v4];
      int idx = 4 * v4 + v4 / 3;        // = g + g/12, g = 4*v4
      stage[idx + 0] = p.x; stage[idx + 1] = p.y;
      stage[idx + 2] = p.z; stage[idx + 3] = p.w;
    }
  } else {
    for (int k = tid; k < nfl; k += 256)
      stage[k + (int)((unsigned)k / 12u)] = pos[3 * t0 + k];
  }
  __syncthreads();

  if (tid == 0) {
    // ---- FZ: closed-form algebra from tot -> sc (block-local) ----------
    const int C = ncp[0];
    const float kk = kp[0];
    const float Rf = (float)R;
    const float* xp = &tot[19];
    float inv0 = 1.f / box[0], inv1 = 1.f / box[4], inv2 = 1.f / box[8];
    float ox = tot[0], oy = tot[1], oz = tot[2];
    float Fx = 0, Fy = 0, Fz = 0;
    float T1x = 0, T1y = 0, T1z = 0, T2x = 0, T2y = 0, T2z = 0;
    for (int c = 0; c < C; ++c) {
      float nrec = tot[3 + c];
      const float* a = &tot[22 + c * 10];
      float np = a[9];
      float invn = 1.f / np;
      float pcx = a[0] * invn, pcy = a[1] * invn, pcz = a[2] * invn;
      float rcx = a[3] * invn, rcy = a[4] * invn, rcz = a[5] * invn;
      float dx = rcx - pcx, dy = rcy - pcy, dz = rcz - pcz;
      float s3 = rintf(dz * inv2);
      dx -= s3 * box[6]; dy -= s3 * box[7]; dz -= s3 * box[8];
      float s2 = rintf(dy * inv1);
      dx -= s2 * box[3]; dy -= s2 * box[4]; dz -= s2 * box[5];
      float s1 = rintf(dx * inv0);
      float btx = s1 * box[0] + s2 * box[3] + s3 * box[6];
      float bty = s1 * box[1] + s2 * box[4] + s3 * box[7];
      float btz = s1 * box[2] + s2 * box[5] + s3 * box[8];
      sc[W_BT + c * 3 + 0] = btx;
      sc[W_BT + c * 3 + 1] = bty;
      sc[W_BT + c * 3 + 2] = btz;
      ox += nrec * btx; oy += nrec * bty; oz += nrec * btz;
      float SFx = -2.f * kk * (a[6] + np * btx - a[3]);
      float SFy = -2.f * kk * (a[7] + np * bty - a[4]);
      float SFz = -2.f * kk * (a[8] + np * btz - a[5]);
      Fx += SFx; Fy += SFy; Fz += SFz;
      T1x += a[7] * btz - a[8] * bty;
      T1y += a[8] * btx - a[6] * btz;
      T1z += a[6] * bty - a[7] * btx;
      T2x += bty * SFz - btz * SFy;
      T2y += btz * SFx - btx * SFz;
      T2z += btx * SFy - bty * SFx;
    }
    ox /= Rf; oy /= Rf; oz /= Rf;
    float Tx = 2.f * kk * xp[0] - 2.f * kk * T1x + T2x - (oy * Fz - oz * Fy);
    float Ty = 2.f * kk * xp[1] - 2.f * kk * T1y + T2y - (oz * Fx - ox * Fz);
    float Tz = 2.f * kk * xp[2] - 2.f * kk * T1z + T2z - (ox * Fy - oy * Fx);
    sc[W_O + 0] = ox; sc[W_O + 1] = oy; sc[W_O + 2] = oz;
    sc[W_FM + 0] = Fx / Rf; sc[W_FM + 1] = Fy / Rf; sc[W_FM + 2] = Fz / Rf;
    sc[W_TM + 0] = Tx / Rf; sc[W_TM + 1] = Ty / Rf; sc[W_TM + 2] = Tz / Rf;
  }
  __syncthreads();

  const float ox = sc[W_O + 0], oy = sc[W_O + 1], oz = sc[W_O + 2];
  const float fmx = sc[W_FM + 0], fmy = sc[W_FM + 1], fmz = sc[W_FM + 2];
  const float tmx = sc[W_TM + 0], tmy = sc[W_TM + 1], tmz = sc[W_TM + 2];

  uchar mc[4];
  if (nat == 1024) {
    uchar4 m = ((const uchar4*)(inv8 + t0))[tid];
    mc[0] = m.x; mc[1] = m.y; mc[2] = m.z; mc[3] = m.w;
  } else {
#pragma unroll
    for (int q = 0; q < 4; ++q) {
      int la = 4 * tid + q;
      mc[q] = (la < nat) ? inv8[t0 + la] : (uchar)255;
    }
  }
#pragma unroll
  for (int q = 0; q < 4; ++q) {
    int la = 4 * tid + q;
    if (la < nat) {
      float* s = &stage[13 * tid + 3 * q];
      float fx = 0.f, fy = 0.f, fz = 0.f;
      int c = mc[q];
      if (c != 255) {
        float cx = s[0] + sc[W_BT + 3 * c + 0] - ox;
        float cy = s[1] + sc[W_BT + 3 * c + 1] - oy;
        float cz = s[2] + sc[W_BT + 3 * c + 2] - oz;
        float inv = 1.f / (cx * cx + cy * cy + cz * cz);
        fx = fmx + (tmy * cz - tmz * cy) * inv;
        fy = fmy + (tmz * cx - tmx * cz) * inv;
        fz = fmz + (tmx * cy - tmy * cx) * inv;
      }
      s[0] = fx; s[1] = fy; s[2] = fz;   // own slots only: no extra barrier
    }
  }
  __syncthreads();

  if (blockIdx.x == 0 && tid == 0) out[0] = 0.f;  // energy scalar
  float* ob = out + 1 + 3 * t0;
  if (nat == 1024) {
    // k = 3 + 4*j, j in [0,767): dwordx4-aligned coalesced stores
#pragma unroll
    for (int kk = 0; kk < 3; ++kk) {
      int j = tid + kk * 256;
      if (j < 767) {
        int k = 3 + 4 * j;
        float4 v;
        v.x = stage[k + k / 12];
        v.y = stage[(k + 1) + (k + 1) / 12];
        v.z = stage[(k + 2) + (k + 2) / 12];
        v.w = stage[(k + 3) + (k + 3) / 12];
        *(float4*)(ob + k) = v;
      }
    }
    if (tid < 3) ob[tid] = stage[tid];               // k=0,1,2 (k/12 = 0)
    if (tid == 3) ob[3071] = stage[3071 + 3071 / 12];
  } else {
    for (int k = tid; k < nfl; k += 256)
      ob[k] = stage[k + (int)((unsigned)k / 12u)];
  }
}

extern "C" void kernel_launch(void* const* d_in, const int* in_sizes, int n_in,
                              void* d_out, int out_size, void* d_ws, size_t ws_size,
                              hipStream_t stream) {
  const float* pos     = (const float*)d_in[0];
  const float* box     = (const float*)d_in[1];
  const float* ref_poc = (const float*)d_in[2];
  const float* kp      = (const float*)d_in[3];
  const int* rec_idx   = (const int*)d_in[4];
  const int* poc_idx   = (const int*)d_in[5];
  const int* cid       = (const int*)d_in[6];
  const int* poc_cid   = (const int*)d_in[7];
  const int* ncp       = (const int*)d_in[8];
  float* out = (float*)d_out;
  float* ws  = (float*)d_ws;
  uint32* gcount   = (uint32*)((char*)d_ws + GCOUNT_OFF);
  uint32* grecords = (uint32*)((char*)d_ws + REC_OFF);
  uchar*  inv8     = (uchar*)d_ws + INV8_OFF;

  const int N = in_sizes[0] / 3;   // 8M atoms
  const int R = in_sizes[4];       // 2M rec
  const int P = in_sizes[5];       // 500K pocket

  hipMemsetAsync(d_ws, 0, 8192, stream);

  const int nchunk = (R + K1_CHUNK - 1) / K1_CHUNK;
  k_partition<<<nchunk, 256, 0, stream>>>(rec_idx, cid, R, gcount, grecords);
  k_gather<<<1024, 256, 0, stream>>>(pos, ref_poc, rec_idx, poc_idx, poc_cid,
                                     ncp, P, N, gcount, grecords, inv8, ws);
  int gF = (N + 1023) / 1024;
  k_finout<<<gF, 256, 0, stream>>>(pos, inv8, box, kp, ncp, R, N, ws, out);
}